// Round 5
// baseline (276.242 us; speedup 1.0000x reference)
//
#include <hip/hip_runtime.h>

#define IN_DIM 128
#define HID    256
#define NCLS   40
#define BSHIFT 8
#define BSZ    256     // nodes per bucket
#define MAXNB  256     // max buckets (N <= 65536)
#define CHUNK  4096    // edges per scatter block

static inline size_t align256(size_t x) { return (x + 255) & ~(size_t)255; }

__device__ inline unsigned pack_bf16x2(float x, float y) {
    unsigned xb = __float_as_uint(x), yb = __float_as_uint(y);
    unsigned lo = (xb + 0x7fffu + ((xb >> 16) & 1u)) >> 16;
    unsigned hi = (yb + 0x7fffu + ((yb >> 16) & 1u)) >> 16;
    return lo | (hi << 16);
}
__device__ inline unsigned short f2bf(float x) {
    unsigned b = __float_as_uint(x);
    return (unsigned short)((b + 0x7fffu + ((b >> 16) & 1u)) >> 16);
}
__device__ inline float lo16(unsigned u) { return __uint_as_float(u << 16); }
__device__ inline float hi16(unsigned u) { return __uint_as_float(u & 0xffff0000u); }

// ---- K1: bucket histogram ----
__global__ __launch_bounds__(256) void bucket_count_kernel(
        const int* __restrict__ dst, int* __restrict__ bucketCnt, int E, int NB) {
    __shared__ int hist[MAXNB];
    int t = threadIdx.x;
    hist[t] = 0;
    __syncthreads();
    int start = blockIdx.x * CHUNK;
    int cnt = min(CHUNK, E - start);
    for (int i = t; i < cnt; i += 256) atomicAdd(&hist[dst[start + i] >> BSHIFT], 1);
    __syncthreads();
    if (t < NB && hist[t]) atomicAdd(&bucketCnt[t], hist[t]);
}

// ---- K2: scan bucket totals ----
__global__ __launch_bounds__(256) void bucket_scan_kernel(
        const int* __restrict__ bucketCnt, int* __restrict__ bucketBase,
        int* __restrict__ bucketCursor, int* __restrict__ offs, int NB, int N) {
    int t = threadIdx.x, lane = t & 63, wave = t >> 6;
    int v = (t < NB) ? bucketCnt[t] : 0;
    int s = v;
    for (int off = 1; off < 64; off <<= 1) {
        int u = __shfl_up(s, off, 64);
        if (lane >= off) s += u;
    }
    __shared__ int wsum[4];
    if (lane == 63) wsum[wave] = s;
    __syncthreads();
    if (t == 0) {
        int c = 0;
        for (int i = 0; i < 4; ++i) { int x = wsum[i]; wsum[i] = c; c += x; }
    }
    __syncthreads();
    int incl = wsum[wave] + s;
    int excl = incl - v;
    if (t < NB) { bucketBase[t] = excl; bucketCursor[t] = excl; }
    if (t == NB - 1) { bucketBase[NB] = incl; offs[N] = incl; }
}

// ---- K3: bucket-ordered scatter via LDS binning ----
__global__ __launch_bounds__(256) void bucket_scatter_kernel(
        const int* __restrict__ src, const int* __restrict__ dst,
        int* __restrict__ bucketCursor, int2* __restrict__ ebuf, int E) {
    __shared__ int hist[MAXNB], lofs[MAXNB], lcur[MAXNB], gbase[MAXNB];
    __shared__ int2 bin[CHUNK];
    int t = threadIdx.x, lane = t & 63, wave = t >> 6;
    int start = blockIdx.x * CHUNK;
    int cnt = min(CHUNK, E - start);
    hist[t] = 0;
    __syncthreads();
    for (int i = t; i < cnt; i += 256) atomicAdd(&hist[dst[start + i] >> BSHIFT], 1);
    __syncthreads();
    int v = hist[t];
    int s = v;
    for (int off = 1; off < 64; off <<= 1) {
        int u = __shfl_up(s, off, 64);
        if (lane >= off) s += u;
    }
    __shared__ int wsum[4];
    if (lane == 63) wsum[wave] = s;
    __syncthreads();
    if (t == 0) {
        int c = 0;
        for (int i = 0; i < 4; ++i) { int x = wsum[i]; wsum[i] = c; c += x; }
    }
    __syncthreads();
    int excl = wsum[wave] + s - v;
    lofs[t] = excl; lcur[t] = excl;
    if (v) gbase[t] = atomicAdd(&bucketCursor[t], v);
    __syncthreads();
    for (int i = t; i < cnt; i += 256) {
        int s0 = src[start + i], d0 = dst[start + i];
        int r = atomicAdd(&lcur[d0 >> BSHIFT], 1);
        bin[r] = make_int2(s0, d0);
    }
    __syncthreads();
    for (int i = t; i < cnt; i += 256) {
        int2 e = bin[i];
        int b = e.y >> BSHIFT;
        ebuf[gbase[b] + i - lofs[b]] = e;
    }
}

// ---- K4: per-bucket degrees -> offs, norm ----
__global__ __launch_bounds__(256) void build_norm_kernel(
        const int2* __restrict__ ebuf, const int* __restrict__ bucketBase,
        int* __restrict__ offs, float* __restrict__ norm, int N) {
    __shared__ int hist[BSZ];
    int b = blockIdx.x, t = threadIdx.x, lane = t & 63, wave = t >> 6;
    hist[t] = 0;
    __syncthreads();
    int segS = bucketBase[b], segE = bucketBase[b + 1];
    for (int i = segS + t; i < segE; i += 256) atomicAdd(&hist[ebuf[i].y & (BSZ - 1)], 1);
    __syncthreads();
    int v = hist[t];
    int s = v;
    for (int off = 1; off < 64; off <<= 1) {
        int u = __shfl_up(s, off, 64);
        if (lane >= off) s += u;
    }
    __shared__ int wsum[4];
    if (lane == 63) wsum[wave] = s;
    __syncthreads();
    if (t == 0) {
        int c = 0;
        for (int i = 0; i < 4; ++i) { int x = wsum[i]; wsum[i] = c; c += x; }
    }
    __syncthreads();
    int excl = wsum[wave] + s - v;
    int node = b * BSZ + t;
    if (node < N) {
        offs[node] = segS + excl;
        norm[node] = rsqrtf((float)(v > 0 ? v : 1));
    }
}

// ---- K5: per-bucket exact CSR placement with weights ----
__global__ __launch_bounds__(256) void build_csr_kernel(
        const int2* __restrict__ ebuf, const int* __restrict__ bucketBase,
        const int* __restrict__ offs, const float* __restrict__ norm,
        int2* __restrict__ csr, int N) {
    __shared__ int lcur[BSZ];
    __shared__ float snorm[BSZ];
    int b = blockIdx.x, t = threadIdx.x;
    int node = b * BSZ + t;
    lcur[t] = (node < N) ? offs[node] : 0;
    snorm[t] = (node < N) ? norm[node] : 0.f;
    __syncthreads();
    int segS = bucketBase[b], segE = bucketBase[b + 1];
    for (int i = segS + t; i < segE; i += 256) {
        int2 e = ebuf[i];
        int li = e.y & (BSZ - 1);
        float w = norm[e.x] * snorm[li];
        int p = atomicAdd(&lcur[li], 1);
        csr[p] = make_int2(e.x, __float_as_int(w));
    }
}

// ---- fp32 -> bf16x2 cast ----
__global__ void cast_kernel(const float* __restrict__ feat, unsigned* __restrict__ xb, int n) {
    int i = blockIdx.x * blockDim.x + threadIdx.x;
    if (i < n) {
        float2 f = *(const float2*)(feat + (size_t)i * 2);
        xb[i] = pack_bf16x2(f.x, f.y);
    }
}

// ---- propagation: one wave per node, quarter-wave dwordx4 gathers, no barriers ----
__global__ __launch_bounds__(256) void prop_kernel(
        const unsigned* __restrict__ xin, unsigned* __restrict__ xout,
        float* __restrict__ y, const float* __restrict__ feat,
        const int* __restrict__ offs, const int2* __restrict__ csr,
        int first, int N) {
    int t = threadIdx.x;
    int wv = t >> 6, lane = t & 63;
    int q = lane >> 4, ql = lane & 15;
    int v = blockIdx.x * 4 + wv;
    if (v >= N) return;
    __shared__ int2 sIW[4][64];
    int start = offs[v], end = offs[v + 1];
    float a0 = 0.f, a1 = 0.f, a2 = 0.f, a3 = 0.f;
    float a4 = 0.f, a5 = 0.f, a6 = 0.f, a7 = 0.f;
    for (int k = start; k < end; k += 64) {
        int cnt = min(64, end - k);
        if (lane < cnt) sIW[wv][lane] = csr[k + lane];   // same-wave LDS: ordered, no barrier
        int j = 0;
        for (; j + 16 <= cnt; j += 16) {                 // 16 edges: 4 per quarter
            uint4 d[4]; float w[4];
#pragma unroll
            for (int u = 0; u < 4; ++u) {
                int2 e = sIW[wv][j + 4 * u + q];
                w[u] = __int_as_float(e.y);
                d[u] = *(const uint4*)(xin + (size_t)e.x * 64 + ql * 4);
            }
#pragma unroll
            for (int u = 0; u < 4; ++u) {
                a0 += lo16(d[u].x) * w[u]; a1 += hi16(d[u].x) * w[u];
                a2 += lo16(d[u].y) * w[u]; a3 += hi16(d[u].y) * w[u];
                a4 += lo16(d[u].z) * w[u]; a5 += hi16(d[u].z) * w[u];
                a6 += lo16(d[u].w) * w[u]; a7 += hi16(d[u].w) * w[u];
            }
        }
        for (; j < cnt; j += 4) {                        // tail: 1 edge per quarter
            int idx = j + q;
            float w = 0.f; uint4 d = make_uint4(0u, 0u, 0u, 0u);
            if (idx < cnt) {
                int2 e = sIW[wv][idx];
                w = __int_as_float(e.y);
                d = *(const uint4*)(xin + (size_t)e.x * 64 + ql * 4);
            }
            a0 += lo16(d.x) * w; a1 += hi16(d.x) * w;
            a2 += lo16(d.y) * w; a3 += hi16(d.y) * w;
            a4 += lo16(d.z) * w; a5 += hi16(d.z) * w;
            a6 += lo16(d.w) * w; a7 += hi16(d.w) * w;
        }
    }
    // combine quarters (xor-16, xor-32)
    a0 += __shfl_xor(a0, 16, 64); a0 += __shfl_xor(a0, 32, 64);
    a1 += __shfl_xor(a1, 16, 64); a1 += __shfl_xor(a1, 32, 64);
    a2 += __shfl_xor(a2, 16, 64); a2 += __shfl_xor(a2, 32, 64);
    a3 += __shfl_xor(a3, 16, 64); a3 += __shfl_xor(a3, 32, 64);
    a4 += __shfl_xor(a4, 16, 64); a4 += __shfl_xor(a4, 32, 64);
    a5 += __shfl_xor(a5, 16, 64); a5 += __shfl_xor(a5, 32, 64);
    a6 += __shfl_xor(a6, 16, 64); a6 += __shfl_xor(a6, 32, 64);
    a7 += __shfl_xor(a7, 16, 64); a7 += __shfl_xor(a7, 32, 64);
    if (q == 0) {
        uint4 o;
        o.x = pack_bf16x2(a0, a1); o.y = pack_bf16x2(a2, a3);
        o.z = pack_bf16x2(a4, a5); o.w = pack_bf16x2(a6, a7);
        *(uint4*)(xout + (size_t)v * 64 + ql * 4) = o;
        size_t yo = (size_t)v * 128 + ql * 8;
        if (first) {
            float4 f0 = *(const float4*)(feat + yo);
            float4 f1 = *(const float4*)(feat + yo + 4);
            *(float4*)(y + yo)     = make_float4(f0.x + a0, f0.y + a1, f0.z + a2, f0.w + a3);
            *(float4*)(y + yo + 4) = make_float4(f1.x + a4, f1.y + a5, f1.z + a6, f1.w + a7);
        } else {
            float4 f0 = *(const float4*)(y + yo);
            float4 f1 = *(const float4*)(y + yo + 4);
            *(float4*)(y + yo)     = make_float4(f0.x + a0, f0.y + a1, f0.z + a2, f0.w + a3);
            *(float4*)(y + yo + 4) = make_float4(f1.x + a4, f1.y + a5, f1.z + a6, f1.w + a7);
        }
    }
}

// ---- convert/transposed weights to bf16 ----
__global__ void conv_weights_kernel(const float* __restrict__ W1, const float* __restrict__ W2,
                                    unsigned short* __restrict__ W1T, unsigned short* __restrict__ W2T) {
    int i = blockIdx.x * blockDim.x + threadIdx.x;
    if (i < 256 * 128) {
        int n = i >> 7, k = i & 127;
        W1T[i] = f2bf(W1[k * 256 + n]);
    }
    int j = i - 256 * 128;
    if (j >= 0 && j < 48 * 256) {
        int c = j >> 8, k = j & 255;
        W2T[j] = (c < 40) ? f2bf(W2[k * 40 + c]) : (unsigned short)0;
    }
}

// ---- fused MFMA MLP + log_softmax, register-resident weights ----
typedef __attribute__((ext_vector_type(8))) short bf16x8;
typedef __attribute__((ext_vector_type(4))) float f32x4;

#define SA_STRIDE 136
#define SH_STRIDE 264

__global__ __launch_bounds__(256) void mlp_kernel(
        const float* __restrict__ y,
        const unsigned short* __restrict__ W1T, const float* __restrict__ b1,
        const unsigned short* __restrict__ W2T, const float* __restrict__ b2,
        float* __restrict__ out, int N) {
    __shared__ unsigned short sBuf[64 * SH_STRIDE];   // union: sA (first 64*136) then sH
    int t = threadIdx.x, wave = t >> 6, lane = t & 63;
    int n0 = blockIdx.x * 64;
    int l15 = lane & 15, lq = lane >> 4;

    // W1 fragments -> registers (16 independent 16B loads)
    bf16x8 w1f[4][4];
#pragma unroll
    for (int s = 0; s < 4; ++s)
#pragma unroll
        for (int ht = 0; ht < 4; ++ht)
            w1f[s][ht] = *(const bf16x8*)(W1T + ((wave * 64 + ht * 16 + l15) * 128 + s * 32 + lq * 8));

    // stage A tile with float4 loads: 64 nodes x 128 k, *0.25 -> bf16
#pragma unroll
    for (int i = 0; i < 8; ++i) {
        int idx = t + i * 256;             // 0..2047 float4s
        int n = idx >> 5, kp = idx & 31;
        int gv = n0 + n;
        float4 f = make_float4(0.f, 0.f, 0.f, 0.f);
        if (gv < N) f = *(const float4*)(y + (size_t)gv * 128 + kp * 4);
        uint2 o;
        o.x = pack_bf16x2(f.x * 0.25f, f.y * 0.25f);
        o.y = pack_bf16x2(f.z * 0.25f, f.w * 0.25f);
        *(uint2*)&sBuf[n * SA_STRIDE + kp * 4] = o;
    }
    __syncthreads();

    f32x4 acc[4][4];
#pragma unroll
    for (int mt = 0; mt < 4; ++mt)
#pragma unroll
        for (int ht = 0; ht < 4; ++ht) acc[mt][ht] = (f32x4){0.f, 0.f, 0.f, 0.f};

#pragma unroll
    for (int s = 0; s < 4; ++s) {
#pragma unroll
        for (int mt = 0; mt < 4; ++mt) {
            bf16x8 afr = *(const bf16x8*)&sBuf[(mt * 16 + l15) * SA_STRIDE + s * 32 + lq * 8];
#pragma unroll
            for (int ht = 0; ht < 4; ++ht)
                acc[mt][ht] = __builtin_amdgcn_mfma_f32_16x16x32_bf16(afr, w1f[s][ht], acc[mt][ht], 0, 0, 0);
        }
    }
    __syncthreads();   // all sA reads done before sH overwrites the union

    // W2 fragments -> registers (24 independent 16B loads), overlap with sH stores
    bf16x8 w2f[8][3];
#pragma unroll
    for (int s = 0; s < 8; ++s)
#pragma unroll
        for (int ct = 0; ct < 3; ++ct)
            w2f[s][ct] = *(const bf16x8*)(W2T + ((ct * 16 + l15) * 256 + s * 32 + lq * 8));

#pragma unroll
    for (int ht = 0; ht < 4; ++ht) {
        int hid = wave * 64 + ht * 16 + l15;
        float bb = b1[hid];
#pragma unroll
        for (int mt = 0; mt < 4; ++mt) {
#pragma unroll
            for (int r = 0; r < 4; ++r) {
                int node = mt * 16 + lq * 4 + r;
                float h = fmaxf(acc[mt][ht][r] + bb, 0.f);
                sBuf[node * SH_STRIDE + hid] = f2bf(h);
            }
        }
    }
    __syncthreads();

    f32x4 acc2[3];
#pragma unroll
    for (int ct = 0; ct < 3; ++ct) acc2[ct] = (f32x4){0.f, 0.f, 0.f, 0.f};
#pragma unroll
    for (int s = 0; s < 8; ++s) {
        bf16x8 afr = *(const bf16x8*)&sBuf[(wave * 16 + l15) * SH_STRIDE + s * 32 + lq * 8];
#pragma unroll
        for (int ct = 0; ct < 3; ++ct)
            acc2[ct] = __builtin_amdgcn_mfma_f32_16x16x32_bf16(afr, w2f[s][ct], acc2[ct], 0, 0, 0);
    }

    float lg[3][4];
#pragma unroll
    for (int ct = 0; ct < 3; ++ct) {
        int c = ct * 16 + l15;
        float bb = (c < NCLS) ? b2[c] : 0.f;
#pragma unroll
        for (int r = 0; r < 4; ++r) lg[ct][r] = acc2[ct][r] + bb;
    }
#pragma unroll
    for (int r = 0; r < 4; ++r) {
        float m = fmaxf(lg[0][r], lg[1][r]);
        if (l15 < 8) m = fmaxf(m, lg[2][r]);
        for (int off = 1; off < 16; off <<= 1) m = fmaxf(m, __shfl_xor(m, off, 64));
        float ssum = __expf(lg[0][r] - m) + __expf(lg[1][r] - m) +
                     ((l15 < 8) ? __expf(lg[2][r] - m) : 0.f);
        for (int off = 1; off < 16; off <<= 1) ssum += __shfl_xor(ssum, off, 64);
        float ls = m + __logf(ssum);
        int node = n0 + wave * 16 + lq * 4 + r;
        if (node < N) {
#pragma unroll
            for (int ct = 0; ct < 3; ++ct) {
                int c = ct * 16 + l15;
                if (c < NCLS) out[(size_t)node * NCLS + c] = lg[ct][r] - ls;
            }
        }
    }
}

extern "C" void kernel_launch(void* const* d_in, const int* in_sizes, int n_in,
                              void* d_out, int out_size, void* d_ws, size_t ws_size,
                              hipStream_t stream) {
    const float* feat = (const float*)d_in[0];
    const int*   src  = (const int*)d_in[1];
    const int*   dst  = (const int*)d_in[2];
    const float* W1   = (const float*)d_in[3];
    const float* b1   = (const float*)d_in[4];
    const float* W2   = (const float*)d_in[5];
    const float* b2   = (const float*)d_in[6];
    float* out = (float*)d_out;

    int N = in_sizes[0] / IN_DIM;
    int E = in_sizes[1];
    int NB = (N + BSZ - 1) / BSZ;

    char* ws = (char*)d_ws;
    size_t off = 0;
    float* norm   = (float*)(ws + off); off += align256((size_t)N * 4);
    int*   offs   = (int*)(ws + off);   off += align256((size_t)(N + 1) * 4);
    int*   bBase  = (int*)(ws + off);   off += align256((size_t)(MAXNB + 1) * 4);
    int*   bCur   = (int*)(ws + off);   off += align256((size_t)MAXNB * 4);
    int*   bCnt   = (int*)(ws + off);   off += align256((size_t)MAXNB * 4);
    int2*  csr    = (int2*)(ws + off);  off += align256((size_t)E * 8);
    unsigned* xb0 = (unsigned*)(ws + off); off += align256((size_t)N * 64 * 4);
    unsigned* xb1 = (unsigned*)(ws + off); off += align256((size_t)N * 64 * 4);
    float* ybuf   = (float*)(ws + off); off += align256((size_t)N * IN_DIM * 4);
    unsigned short* W1T = (unsigned short*)(ws + off); off += align256((size_t)256 * 128 * 2);
    unsigned short* W2T = (unsigned short*)(ws + off); off += align256((size_t)48 * 256 * 2);
    (void)ws_size;
    int2* ebuf = (int2*)xb1;   // alias: ebuf dead before prop1 writes xb1

    hipMemsetAsync(bCnt, 0, (size_t)MAXNB * 4, stream);

    int echunks = (E + CHUNK - 1) / CHUNK;
    bucket_count_kernel<<<echunks, 256, 0, stream>>>(dst, bCnt, E, NB);
    bucket_scan_kernel<<<1, 256, 0, stream>>>(bCnt, bBase, bCur, offs, NB, N);
    bucket_scatter_kernel<<<echunks, 256, 0, stream>>>(src, dst, bCur, ebuf, E);
    build_norm_kernel<<<NB, 256, 0, stream>>>(ebuf, bBase, offs, norm, N);
    build_csr_kernel<<<NB, 256, 0, stream>>>(ebuf, bBase, offs, norm, csr, N);

    conv_weights_kernel<<<(256 * 128 + 48 * 256 + 255) / 256, 256, 0, stream>>>(W1, W2, W1T, W2T);
    cast_kernel<<<(N * 64 + 255) / 256, 256, 0, stream>>>(feat, xb0, N * 64);

    int pb = (N + 3) / 4;
    prop_kernel<<<pb, 256, 0, stream>>>(xb0, xb1, ybuf, feat, offs, csr, 1, N);
    prop_kernel<<<pb, 256, 0, stream>>>(xb1, xb0, ybuf, feat, offs, csr, 0, N);
    prop_kernel<<<pb, 256, 0, stream>>>(xb0, xb1, ybuf, feat, offs, csr, 0, N);

    mlp_kernel<<<(N + 63) / 64, 256, 0, stream>>>(ybuf, W1T, b1, W2T, b2, out, N);
}